// Round 15
// baseline (361.548 us; speedup 1.0000x reference)
//
#include <hip/hip_runtime.h>
#include <math.h>

// Problem dims: B=8, N=512, T=64, D=128, E=32, M=3, BN=4096
// ws layout (float offsets)
#define OFF_U      0          // 384
#define OFF_C      384        // 384
#define OFF_QWHI   768        // 6144 floats = 12288 bf16 (qn@spaceW hi)
#define OFF_QWLO   6912       // 6144 floats (lo)
#define OFF_H      13056      // 4096*128
#define OFF_PROBS  537344     // 24
#define OFF_SYNC   537368     // 2 unsigned counters (free slots after probs)
#define OFF_HV     537376     // 4096
#define OFF_SCORES 541472     // 768*512
#define OFF_HMIX   934688     // 8*32*512 = 131072
#define OFF_WHI    1066016    // 24576 floats = 49152 bf16 (Whh bf16)
#define OFF_SHI    1115168    // 24576 floats (spaceW hi)
#define OFF_SLO    1139744    // 24576 floats (spaceW lo)
#define OFF_STATS  1164320    // 256 blocks * 256 floats
#define OFF_EV     1229856    // 256
#define OFF_QB     1230112    // 96 (qn . spaceb)

typedef short bf16x8 __attribute__((ext_vector_type(8)));
typedef float f32x4 __attribute__((ext_vector_type(4)));

union U8 { unsigned short s[8]; bf16x8 v; uint4 u4; };

__device__ __forceinline__ unsigned short bf16_rtn(float f) {
  unsigned int u = __float_as_uint(f);
  return (unsigned short)((u + 0x7FFFu + ((u >> 16) & 1u)) >> 16);
}
__device__ __forceinline__ float bf16_f(unsigned short h) {
  return __uint_as_float(((unsigned int)h) << 16);
}

// Spin barrier among co-resident blocks (grid waves << CU capacity).
__device__ __forceinline__ void spin_sync(unsigned* ctr, unsigned target, int tid) {
  __threadfence();     // release prior global writes, device scope
  __syncthreads();
  if (tid == 0) {
    __hip_atomic_fetch_add(ctr, 1u, __ATOMIC_ACQ_REL, __HIP_MEMORY_SCOPE_AGENT);
    while (__hip_atomic_load(ctr, __ATOMIC_ACQUIRE, __HIP_MEMORY_SCOPE_AGENT) < target)
      __builtin_amdgcn_s_sleep(4);
  }
  __syncthreads();
  __threadfence();     // acquire side: invalidate for this block's readers
}

// ---------------------------------------------------------------------------
// prep: 112 blocks x 256. Only what gru itself consumes:
// 0..95: u/c (one wave per Wih row); 96..111: Whh bf16 plane.
// ---------------------------------------------------------------------------
__global__ __launch_bounds__(256) void prep_kernel(const float* __restrict__ Wih,
                                                   const float* __restrict__ projW,
                                                   const float* __restrict__ projb,
                                                   const float* __restrict__ bih,
                                                   const float* __restrict__ Whh,
                                                   float* __restrict__ ws) {
  const int bid = blockIdx.x, tid = threadIdx.x;
  const int wave = tid >> 6, lane = tid & 63;
  if (bid < 96) {
    int r = bid * 4 + wave;  // [0,384)
    float w0 = Wih[r * 128 + lane], w1 = Wih[r * 128 + 64 + lane];
    float u = w0 * projW[lane] + w1 * projW[64 + lane];
    float c = w0 * projb[lane] + w1 * projb[64 + lane];
    for (int off = 32; off; off >>= 1) {
      u += __shfl_xor(u, off);
      c += __shfl_xor(c, off);
    }
    if (lane == 0) {
      ws[OFF_U + r] = u;
      ws[OFF_C + r] = c + bih[r];
    }
  } else {
    unsigned short* WHI = (unsigned short*)(ws + OFF_WHI);
    int base = (bid - 96) * 3072;
    for (int i = tid; i < 3072; i += 256)
      WHI[base + i] = bf16_rtn(Whh[base + i]);
  }
}

// ---------------------------------------------------------------------------
// GRU (R14-verified core, blocks 0..255) + concurrent prep extras
// (blocks 256..368: spaceW split, QW/qb, ev+counter zero).
// ---------------------------------------------------------------------------
__global__ __launch_bounds__(512, 2) void gru_kernel(const float* __restrict__ x,
                                                     const float* __restrict__ bhh,
                                                     const float* __restrict__ outW,
                                                     const float* __restrict__ spaceW,
                                                     const float* __restrict__ spaceb,
                                                     const float* __restrict__ queries,
                                                     float* __restrict__ ws) {
  __shared__ __align__(16) unsigned short hB[2][16 * 17 * 8];
  __shared__ float xsAll[16 * 65];
  __shared__ float hFin[16 * 132];
  __shared__ float invS, qdS;

  const int tid = threadIdx.x, wave = tid >> 6, lane = tid & 63;

  if (blockIdx.x >= 256) {
    const int xb = blockIdx.x - 256;
    if (xb < 16) {            // spaceW hi/lo split
      unsigned short* SHI = (unsigned short*)(ws + OFF_SHI);
      unsigned short* SLO = (unsigned short*)(ws + OFF_SLO);
      int base = xb * 3072;
      for (int i = tid; i < 3072; i += 512) {
        float w = spaceW[base + i];
        unsigned short hi = bf16_rtn(w);
        SHI[base + i] = hi;
        SLO[base + i] = bf16_rtn(w - bf16_f(hi));
      }
    } else if (xb < 112) {    // QW rows
      int qi = xb - 16;       // 0..95
      int m = qi >> 5, e = qi & 31;
      const float* qrow = queries + (m * 32 + e) * 128;
      if (wave == 0) {
        float v0 = qrow[lane], v1 = qrow[64 + lane];
        float ss = v0 * v0 + v1 * v1;
        for (int off = 32; off; off >>= 1) ss += __shfl_xor(ss, off);
        if (lane == 0) invS = 1.f / fmaxf(sqrtf(ss), 1e-12f);
      } else if (wave == 1) {
        float v = qrow[lane] * spaceb[m * 128 + lane] +
                  qrow[64 + lane] * spaceb[m * 128 + 64 + lane];
        for (int off = 32; off; off >>= 1) v += __shfl_xor(v, off);
        if (lane == 0) qdS = v;
      }
      __syncthreads();
      if (tid < 128) {
        int din = tid;
        float acc = 0.f;
        for (int dout = 0; dout < 128; ++dout)
          acc += qrow[dout] * spaceW[m * 16384 + dout * 128 + din];
        acc *= invS;
        unsigned short hi = bf16_rtn(acc);
        ((unsigned short*)(ws + OFF_QWHI))[(m * 32 + e) * 128 + din] = hi;
        ((unsigned short*)(ws + OFF_QWLO))[(m * 32 + e) * 128 + din] =
            bf16_rtn(acc - bf16_f(hi));
      }
      if (tid == 0) ws[OFF_QB + m * 32 + e] = qdS * invS;
    } else {                  // ev + sync counters zero
      if (tid < 256) ws[OFF_EV + tid] = 0.f;
      if (tid == 256) ((unsigned*)(ws + OFF_SYNC))[0] = 0u;
      if (tid == 257) ((unsigned*)(ws + OFF_SYNC))[1] = 0u;
    }
    return;
  }

  const int q = lane >> 4, s15 = lane & 15;
  const int d = wave * 16 + s15;
  const unsigned short* WHI = (const unsigned short*)(ws + OFF_WHI);

  {
    float4 z4 = make_float4(0.f, 0.f, 0.f, 0.f);
    float4* hm4 = (float4*)(ws + OFF_HMIX);
    if (tid < 128) hm4[blockIdx.x * 128 + tid] = z4;
  }

  bf16x8 Bh[3][4];
#pragma unroll
  for (int t = 0; t < 3; ++t) {
    int row = (wave + 8 * t) * 16 + s15;
#pragma unroll
    for (int c = 0; c < 4; ++c)
      Bh[t][c] = *(const bf16x8*)&WHI[row * 128 + c * 32 + q * 8];
  }
  const float ur = ws[OFF_U + d],       uz = ws[OFF_U + 128 + d], un = ws[OFF_U + 256 + d];
  const float cr = ws[OFF_C + d] + bhh[d];
  const float cz = ws[OFF_C + 128 + d] + bhh[128 + d];
  const float cn = ws[OFF_C + 256 + d];
  const float bj2 = bhh[256 + d];

  const int seq0 = blockIdx.x * 16;
  for (int i = tid; i < 1024; i += 512) {
    int s = i >> 6, tt = i & 63;
    int r = (seq0 + s) * 64 + tt;
    xsAll[s * 65 + tt] = x[((r >> 15) * 512 + (r & 511)) * 64 + ((r >> 9) & 63)];
  }
  for (int i = tid; i < 2176; i += 512) hB[0][i] = 0;
  __syncthreads();

  float hreg[4] = {0.f, 0.f, 0.f, 0.f};
  const int g = d >> 3, e = d & 7;

  for (int t = 0; t < 64; ++t) {
    const int rb = t & 1, wb = rb ^ 1;
    f32x4 acc0 = {0.f, 0.f, 0.f, 0.f};
    f32x4 acc1 = {0.f, 0.f, 0.f, 0.f};
    f32x4 acc2 = {0.f, 0.f, 0.f, 0.f};
#pragma unroll
    for (int c = 0; c < 4; ++c) {
      bf16x8 A = *(const bf16x8*)&hB[rb][((c * 4 + q) * 17 + s15) * 8];
      acc0 = __builtin_amdgcn_mfma_f32_16x16x32_bf16(A, Bh[0][c], acc0, 0, 0, 0);
      acc1 = __builtin_amdgcn_mfma_f32_16x16x32_bf16(A, Bh[1][c], acc1, 0, 0, 0);
      acc2 = __builtin_amdgcn_mfma_f32_16x16x32_bf16(A, Bh[2][c], acc2, 0, 0, 0);
    }
    float xsv[4];
#pragma unroll
    for (int r = 0; r < 4; ++r) xsv[r] = xsAll[(q * 4 + r) * 65 + t];
#pragma unroll
    for (int r = 0; r < 4; ++r) {
      int s = q * 4 + r;
      float gr = fmaf(xsv[r], ur, cr + acc0[r]);
      float gz = fmaf(xsv[r], uz, cz + acc1[r]);
      float gn = fmaf(xsv[r], un, cn);
      float hn = acc2[r] + bj2;
      float rr = __builtin_amdgcn_rcpf(1.f + __expf(-gr));
      float zm = __builtin_amdgcn_rcpf(1.f + __expf(gz));   // 1 - sigmoid(gz)
      float a = fmaf(rr, hn, gn);
      float ng = 1.f - 2.f * __builtin_amdgcn_rcpf(__expf(2.f * a) + 1.f);
      float hv = fmaf(zm, ng - hreg[r], hreg[r]);           // (1-z)*ng + z*h
      hreg[r] = hv;
      hB[wb][(g * 17 + s) * 8 + e] = bf16_rtn(hv);
    }
    __syncthreads();
  }

#pragma unroll
  for (int r = 0; r < 4; ++r) hFin[(q * 4 + r) * 132 + d] = hreg[r];
  __syncthreads();
  float* h_out = ws + OFF_H;
#pragma unroll
  for (int p = 0; p < 4; ++p) {
    int item = tid + p * 512;
    int s = item >> 7, dd = item & 127;
    h_out[(seq0 + s) * 128 + dd] = hFin[s * 132 + dd];
  }
  for (int s = wave * 2; s < wave * 2 + 2; ++s) {
    float a = hFin[s * 132 + lane] * outW[lane] + hFin[s * 132 + 64 + lane] * outW[64 + lane];
    for (int off = 32; off; off >>= 1) a += __shfl_xor(a, off);
    if (lane == 0) ws[OFF_HV + seq0 + s] = a;
  }
  if (tid < 128) {
    float s = 0.f, q2 = 0.f;
#pragma unroll
    for (int sI = 0; sI < 16; ++sI) {
      float v = hFin[sI * 132 + tid];
      s += v; q2 += v * v;
    }
    ws[OFF_STATS + blockIdx.x * 256 + tid] = s;
    ws[OFF_STATS + blockIdx.x * 256 + 128 + tid] = q2;
  }
}

// ---------------------------------------------------------------------------
// megatail: 384 blocks x 256. scores(+probs) -> spin-sync -> topk(+ev)
// -> spin-sync -> final. All phase bodies are R13/R14-verified.
// ---------------------------------------------------------------------------
__global__ __launch_bounds__(256) void megatail_kernel(const float* __restrict__ spaceb,
                                                       const float* __restrict__ routerW,
                                                       const float* __restrict__ routerb,
                                                       const float* __restrict__ prior,
                                                       const float* __restrict__ outb,
                                                       const float* __restrict__ plog,
                                                       float* __restrict__ ws,
                                                       float* __restrict__ d_out) {
  const int bid = blockIdx.x;
  const int tid = threadIdx.x, wave = tid >> 6, lane = tid & 63;
  const int q = lane >> 4, s15 = lane & 15;

  __shared__ __align__(16) unsigned short sHi[16 * 33 * 8];
  __shared__ __align__(16) unsigned short sLo[16 * 33 * 8];
  __shared__ float hsL[32 * 132];
  __shared__ float biasL[128];
  __shared__ float invnL[32];
  __shared__ float qbL[32];

  unsigned* ctr = (unsigned*)(ws + OFF_SYNC);

  // ================= Phase A: scores =================
  {
    const int chunk = bid & 15, m = (bid >> 4) % 3, b = bid / 48;
    const int n0 = chunk * 32;
    const float* hG = ws + OFF_H;
    const unsigned short* SHI = (const unsigned short*)(ws + OFF_SHI);
    const unsigned short* SLO = (const unsigned short*)(ws + OFF_SLO);
    const unsigned short* QWHI = (const unsigned short*)(ws + OFF_QWHI);
    const unsigned short* QWLO = (const unsigned short*)(ws + OFF_QWLO);

    if (tid < 128) biasL[tid] = spaceb[m * 128 + tid];
    else if (tid < 160) qbL[tid - 128] = ws[OFF_QB + m * 32 + (tid - 128)];
    {
      int nn = tid >> 3, kc = tid & 7;
      const float* row = &hG[(b * 512 + n0 + nn) * 128 + kc * 16];
      U8 ph0, pl0, ph1, pl1;
#pragma unroll
      for (int j = 0; j < 8; ++j) {
        float v = row[j];
        unsigned short hi = bf16_rtn(v);
        ph0.s[j] = hi; pl0.s[j] = bf16_rtn(v - bf16_f(hi));
      }
#pragma unroll
      for (int j = 0; j < 8; ++j) {
        float v = row[8 + j];
        unsigned short hi = bf16_rtn(v);
        ph1.s[j] = hi; pl1.s[j] = bf16_rtn(v - bf16_f(hi));
      }
      int g0 = kc * 2;
      *(uint4*)&sHi[(g0 * 33 + nn) * 8] = ph0.u4;
      *(uint4*)&sLo[(g0 * 33 + nn) * 8] = pl0.u4;
      *(uint4*)&sHi[((g0 + 1) * 33 + nn) * 8] = ph1.u4;
      *(uint4*)&sLo[((g0 + 1) * 33 + nn) * 8] = pl1.u4;
    }
    __syncthreads();

    const int nt = wave >> 1;
    const int half = wave & 1;
    const int dt0 = half * 4;
    f32x4 acc[4] = {{0.f,0.f,0.f,0.f},{0.f,0.f,0.f,0.f},{0.f,0.f,0.f,0.f},{0.f,0.f,0.f,0.f}};
    f32x4 accS = {0.f, 0.f, 0.f, 0.f};
#pragma unroll
    for (int c = 0; c < 4; ++c) {
      bf16x8 Ahi = *(const bf16x8*)&sHi[((c * 4 + q) * 33 + nt * 16 + s15) * 8];
      bf16x8 Alo = *(const bf16x8*)&sLo[((c * 4 + q) * 33 + nt * 16 + s15) * 8];
#pragma unroll
      for (int i = 0; i < 4; ++i) {
        int row = m * 16384 + ((dt0 + i) * 16 + s15) * 128 + c * 32 + q * 8;
        bf16x8 Bhi = *(const bf16x8*)&SHI[row];
        bf16x8 Blo = *(const bf16x8*)&SLO[row];
        acc[i] = __builtin_amdgcn_mfma_f32_16x16x32_bf16(Ahi, Bhi, acc[i], 0, 0, 0);
        acc[i] = __builtin_amdgcn_mfma_f32_16x16x32_bf16(Alo, Bhi, acc[i], 0, 0, 0);
        acc[i] = __builtin_amdgcn_mfma_f32_16x16x32_bf16(Ahi, Blo, acc[i], 0, 0, 0);
      }
      {
        int row = (m * 32 + half * 16 + s15) * 128 + c * 32 + q * 8;
        bf16x8 Qhi = *(const bf16x8*)&QWHI[row];
        bf16x8 Qlo = *(const bf16x8*)&QWLO[row];
        accS = __builtin_amdgcn_mfma_f32_16x16x32_bf16(Ahi, Qhi, accS, 0, 0, 0);
        accS = __builtin_amdgcn_mfma_f32_16x16x32_bf16(Alo, Qhi, accS, 0, 0, 0);
        accS = __builtin_amdgcn_mfma_f32_16x16x32_bf16(Ahi, Qlo, accS, 0, 0, 0);
      }
    }
#pragma unroll
    for (int i = 0; i < 4; ++i) {
      int dcol = (dt0 + i) * 16 + s15;
      float bb = biasL[dcol];
#pragma unroll
      for (int r = 0; r < 4; ++r)
        hsL[(nt * 16 + q * 4 + r) * 132 + dcol] = acc[i][r] + bb;
    }
    __syncthreads();

    {
      int n = tid >> 3, kc = tid & 7;
      float ss = 0.f;
#pragma unroll
      for (int d4 = 0; d4 < 4; ++d4) {
        float4 v = *(const float4*)&hsL[n * 132 + kc * 16 + d4 * 4];
        ss += v.x * v.x + v.y * v.y + v.z * v.z + v.w * v.w;
      }
      ss += __shfl_xor(ss, 1); ss += __shfl_xor(ss, 2); ss += __shfl_xor(ss, 4);
      if (kc == 0) invnL[n] = 1.f / fmaxf(sqrtf(ss), 1e-12f);
    }
    __syncthreads();

    {
      int e = half * 16 + s15;
      float qb = qbL[e];
      int nb = nt * 16 + q * 4;
      float4 o;
      o.x = (accS[0] + qb) * invnL[nb + 0];
      o.y = (accS[1] + qb) * invnL[nb + 1];
      o.z = (accS[2] + qb) * invnL[nb + 2];
      o.w = (accS[3] + qb) * invnL[nb + 3];
      *(float4*)&ws[OFF_SCORES + ((b * 3 + m) * 32 + e) * 512 + n0 + nb] = o;
    }

    if ((bid % 48) == 0) {
      __syncthreads();
      float* st = hsL;
      float* lgS = hsL + 256;
      if (tid < 128) {
        float s = 0.f, q2 = 0.f;
        const float* base = ws + OFF_STATS + b * 32 * 256;
        for (int j = 0; j < 32; ++j) {
          s += base[j * 256 + tid];
          q2 += base[j * 256 + 128 + tid];
        }
        float mean = s * (1.f / 512.f);
        float var = (q2 - 512.f * mean * mean) * (1.f / 511.f);  // ddof=1
        st[tid] = mean;
        st[128 + tid] = sqrtf(fmaxf(var, 0.f));
      }
      __syncthreads();
      if (tid < 3) {
        float acc2 = routerb[tid];
        for (int k = 0; k < 256; ++k) acc2 += st[k] * routerW[tid * 256 + k];
        lgS[tid] = acc2;
      }
      __syncthreads();
      if (tid == 0) {
        float mx = fmaxf(lgS[0], fmaxf(lgS[1], lgS[2]));
        float e0 = expf(lgS[0] - mx), e1 = expf(lgS[1] - mx), e2 = expf(lgS[2] - mx);
        float inv = 1.f / (e0 + e1 + e2);
        ws[OFF_PROBS + b * 3 + 0] = e0 * inv;
        ws[OFF_PROBS + b * 3 + 1] = e1 * inv;
        ws[OFF_PROBS + b * 3 + 2] = e2 * inv;
        d_out[4096 + b * 3 + 0] = e0 * inv;
        d_out[4096 + b * 3 + 1] = e1 * inv;
        d_out[4096 + b * 3 + 2] = e2 * inv;
      }
    }
  }

  spin_sync(&ctr[0], 384u, tid);

  // ================= Phase B: topk (rows bid*2, bid*2+1) =================
  {
    const int b = bid / 48;
    for (int i = tid; i < 512; i += 256) hsL[i] = ws[OFF_HV + b * 512 + i];
    __syncthreads();
    if (wave < 2) {
      int row = bid * 2 + wave;
      int m = (row / 32) % 3, e = row & 31;
      const float* sc = ws + OFF_SCORES + row * 512;
      float prob = ws[OFF_PROBS + b * 3 + m];
      float v[8];
#pragma unroll
      for (int j = 0; j < 8; ++j) v[j] = sc[j * 64 + lane];
      float selv = 0.f; int seli = 0; float maxv = 0.f;
      for (int it = 0; it < 25; ++it) {
        float bv = v[0]; int bj = 0;
#pragma unroll
        for (int j = 1; j < 8; ++j)
          if (v[j] > bv) { bv = v[j]; bj = j; }
        int bidx = bj * 64 + lane;
        for (int off = 32; off; off >>= 1) {
          float ov = __shfl_xor(bv, off);
          int oi = __shfl_xor(bidx, off);
          if (ov > bv || (ov == bv && oi < bidx)) { bv = ov; bidx = oi; }
        }
        if (lane == (bidx & 63)) v[bidx >> 6] = -INFINITY;
        if (it == 0) maxv = bv;
        if (lane == it) { selv = bv; seli = bidx; }
      }
      float ex = (lane < 25) ? __expf((selv - maxv) * (1.f / 0.7f)) : 0.f;
      float den = ex;
      for (int off = 32; off; off >>= 1) den += __shfl_xor(den, off);
      float w = prob * ex / den;  // 0 for lanes >= 25
      if (lane < 25)
        atomicAdd(&ws[OFF_HMIX + (b * 32 + e) * 512 + seli], w);
      float evc = (lane < 25) ? w * hsL[seli] : 0.f;
      for (int off = 32; off; off >>= 1) evc += __shfl_xor(evc, off);
      if (lane == 0) atomicAdd(&ws[OFF_EV + b * 32 + e], evc);
    }
  }

  spin_sync(&ctr[1], 384u, tid);

  // ================= Phase C: final (4096 rows over 1536 waves) ==========
  {
    float alpha = 1.f / (1.f + expf(-plog[0]));
    float ob = outb[0];
    const int gw = bid * 4 + wave;
    for (int row = gw; row < 4096; row += 1536) {
      int b = row >> 9, n = row & 511;
      const float* hv = ws + OFF_HV + b * 512;
      const float* pr = prior + n * 512;
      float s1 = 0.f;
#pragma unroll
      for (int j = 0; j < 8; ++j) s1 += pr[j * 64 + lane] * hv[j * 64 + lane];
      float s2 = 0.f;
      if (lane < 32)
        s2 = ws[OFF_HMIX + (b * 32 + lane) * 512 + n] * ws[OFF_EV + b * 32 + lane];
      float a = alpha * s1 + (1.f - alpha) * s2;
      for (int off = 32; off; off >>= 1) a += __shfl_xor(a, off);
      if (lane == 0) d_out[row] = a + ob;
    }
  }
}

// ---------------------------------------------------------------------------
extern "C" void kernel_launch(void* const* d_in, const int* in_sizes, int n_in,
                              void* d_out, int out_size, void* d_ws, size_t ws_size,
                              hipStream_t stream) {
  const float* x       = (const float*)d_in[0];
  const float* prior   = (const float*)d_in[1];
  const float* projW   = (const float*)d_in[2];
  const float* projb   = (const float*)d_in[3];
  const float* Wih     = (const float*)d_in[4];
  const float* Whh     = (const float*)d_in[5];
  const float* bih     = (const float*)d_in[6];
  const float* bhh     = (const float*)d_in[7];
  const float* spaceW  = (const float*)d_in[8];
  const float* spaceb  = (const float*)d_in[9];
  const float* routerW = (const float*)d_in[10];
  const float* routerb = (const float*)d_in[11];
  const float* outW    = (const float*)d_in[12];
  const float* outb    = (const float*)d_in[13];
  const float* plog    = (const float*)d_in[14];
  const float* queries = (const float*)d_in[15];
  float* ws  = (float*)d_ws;
  float* out = (float*)d_out;

  prep_kernel<<<112, 256, 0, stream>>>(Wih, projW, projb, bih, Whh, ws);
  gru_kernel<<<369, 512, 0, stream>>>(x, bhh, outW, spaceW, spaceb, queries, ws);
  megatail_kernel<<<384, 256, 0, stream>>>(spaceb, routerW, routerb, prior,
                                           outb, plog, ws, out);
}